// Round 4
// baseline (2736.559 us; speedup 1.0000x reference)
//
#include <hip/hip_runtime.h>
#include <hip/hip_bf16.h>
#include <math.h>

#define TT 512
#define BB 128
#define DD 256
#define HH 512
#define EPSF 1e-7f
#define NBG 8     // b-groups of 16 rows (independent LSTM chains)
#define NKS 16    // k-slices of 32 cols per b-group

typedef unsigned int u32;
typedef unsigned short u16;
typedef __attribute__((ext_vector_type(8))) short bf16x8;
typedef __attribute__((ext_vector_type(4))) float f32x4;
typedef __attribute__((ext_vector_type(4))) u32 u32x4;

__device__ __forceinline__ u16 f2b(float x){
  __hip_bfloat16 b = __float2bfloat16(x);
  union { __hip_bfloat16 h; u16 u; } c; c.h = b; return c.u;
}
__device__ __forceinline__ bf16x8 as_b8(u32x4 u){
  union { u32x4 a; bf16x8 b; } c; c.a = u; return c.b;
}
// system-scope (MALL-coherent) ops: bypass L1+L2, no wbl2/inv needed anywhere
__device__ __forceinline__ void st16_sys(void* p, u32x4 v){
  asm volatile("global_store_dwordx4 %0, %1, off sc0 sc1" :: "v"(p), "v"(v) : "memory");
}
__device__ __forceinline__ u32x4 ld16_sys(const void* p){
  u32x4 r;
  asm volatile("global_load_dwordx4 %0, %1, off sc0 sc1" : "=v"(r) : "v"(p) : "memory");
  return r;
}
__device__ __forceinline__ void st4_sys(void* p, u32 v){
  asm volatile("global_store_dword %0, %1, off sc0 sc1" :: "v"(p), "v"(v) : "memory");
}
__device__ __forceinline__ u32 ld4_sys(const void* p){
  u32 r;
  asm volatile("global_load_dword %0, %1, off sc0 sc1" : "=v"(r) : "v"(p) : "memory");
  return r;
}

// ---------------------------------------------------------------------------
// Setup: masks zx/zh, combined bias, bf16 Wx/Wh, zeroed per-block flags.
// ---------------------------------------------------------------------------
__global__ void setup_kernel(const float* __restrict__ ux, const float* __restrict__ uh,
                             const float* __restrict__ p_logit,
                             const float* __restrict__ bx, const float* __restrict__ bh,
                             const float* __restrict__ Wx, const float* __restrict__ Wh,
                             float* __restrict__ zx, float* __restrict__ zh,
                             float* __restrict__ bias,
                             u16* __restrict__ wxb, u16* __restrict__ whb,
                             u32* __restrict__ flags){
  const int i = blockIdx.x*256 + threadIdx.x;
  const float p = 1.0f/(1.0f+expf(-p_logit[0]));
  const float lp = logf(p+EPSF) - logf(1.0f-p+EPSF);
  const float inv1mp = 1.0f/(1.0f-p);
  const int S1 = 4*BB*DD;             // zx end      131072
  const int S2 = S1 + 4*BB*HH;        // zh end      393216
  const int S3 = S2 + 4*HH;           // bias end    395264
  const int S4 = S3 + 4*HH*DD;        // wxb end     919552
  const int S5 = S4 + 4*HH*HH;        // whb end     1968128
  const int S6 = S5 + TT*NBG*16;      // flags end   2033664
  if (i < S1){
    float u = ux[i];
    float l = (lp + logf(u+EPSF) - logf(1.0f-u+EPSF)) * 10.0f;  // /TEMP
    zx[i] = (1.0f - 1.0f/(1.0f+expf(-l))) * inv1mp;
  } else if (i < S2){
    int j = i - S1;
    float u = uh[j];
    float l = (lp + logf(u+EPSF) - logf(1.0f-u+EPSF)) * 10.0f;
    zh[j] = (1.0f - 1.0f/(1.0f+expf(-l))) * inv1mp;
  } else if (i < S3){
    int j = i - S2;
    bias[j] = bx[j] + bh[j];
  } else if (i < S4){
    int j = i - S3;
    wxb[j] = f2b(Wx[j]);
  } else if (i < S5){
    int j = i - S4;
    whb[j] = f2b(Wh[j]);
  } else if (i < S6){
    flags[i - S5] = 0u;
  }
}

// ---------------------------------------------------------------------------
// xim[t][g][b][d] = bf16(input[t][b][d] * zx[g][b][d]); input read once.
// ---------------------------------------------------------------------------
__global__ void xim_kernel(const float* __restrict__ input, const float* __restrict__ zx,
                           u16* __restrict__ xim){
  const int i = blockIdx.x*256 + threadIdx.x;   // (t,b,d-octet)
  const int d = (i & 31) * 8;
  const int rest = i >> 5;             // t*BB + b
  const int b = rest & (BB-1);
  const int t = rest >> 7;
  const float* ip = input + ((size_t)t*BB + b)*DD + d;
  const float4 x0 = *(const float4*)ip;
  const float4 x1 = *(const float4*)(ip+4);
  #pragma unroll
  for (int g = 0; g < 4; g++){
    const float* zp = zx + ((size_t)g*BB + b)*DD + d;
    const float4 z0 = *(const float4*)zp;
    const float4 z1 = *(const float4*)(zp+4);
    union { u16 s[8]; uint4 v; } o;
    o.s[0]=f2b(x0.x*z0.x); o.s[1]=f2b(x0.y*z0.y); o.s[2]=f2b(x0.z*z0.z); o.s[3]=f2b(x0.w*z0.w);
    o.s[4]=f2b(x1.x*z1.x); o.s[5]=f2b(x1.y*z1.y); o.s[6]=f2b(x1.z*z1.z); o.s[7]=f2b(x1.w*z1.w);
    *(uint4*)(xim + (((size_t)t*4 + g)*BB + b)*DD + d) = o.v;
  }
}

// ---------------------------------------------------------------------------
// Persistent LSTM: 128 blocks = 8 b-groups(16 b) x 16 k-slices(32 k).
// 512 threads = 8 waves = (gate g) x (K-half qh). Weights register-resident.
// Sync: per-block flag STOREs (no RMW); wave 7 polls all 16 flags with one
// coalesced 64B load; wave 0 runs the whole epilogue (8 cells/lane) and
// stores hm directly (16B/gate), drains, stores its flag; hn stores after.
// ---------------------------------------------------------------------------
__global__ __launch_bounds__(512, 2)
void lstm_persist(const u16* __restrict__ xim,   // [T][4][B][D]
                  const u16* __restrict__ whb,   // [4][H][H]
                  const u16* __restrict__ wxb,   // [4][H][D]
                  const float* __restrict__ zh,  // [4][B][H]
                  const float* __restrict__ bias,// [4][H]
                  u16* __restrict__ hmg,         // [2][NBG][4][16][H]
                  u32* __restrict__ flags,       // [T][NBG][16]
                  float* __restrict__ hn,        // [T][B][H]
                  float* __restrict__ htc)       // [2][B][H]
{
  __shared__ float pl[8][16][36];    // partial gates [wid][b_local][k_local] (padded)
  __shared__ float zhl[4][16][32];   // zh slice for epilogue
  __shared__ float bl[4][32];        // bias slice

  const int bid = blockIdx.x;
  const int bg = bid & 7, ks = bid >> 3;
  const int b0 = bg*16, k0 = ks*32;
  const int tid = threadIdx.x;
  const int wid = tid >> 6, lane = tid & 63;
  const int g = wid & 3, qh = wid >> 2;
  const int arow = lane & 15, kq = lane >> 4;

  // ---- stage zh/bias into LDS (once) ----
  {
    const int gg = tid >> 7, b = (tid >> 3) & 15, k4 = (tid & 7) * 4;
    *(float4*)&zhl[gg][b][k4] =
        *(const float4*)&zh[((size_t)gg*BB + b0 + b)*HH + k0 + k4];
    if (tid < 128)
      bl[tid>>5][tid&31] = bias[(tid>>5)*HH + k0 + (tid&31)];
  }

  // ---- weights into registers ----
  u32x4 whf[2][8], wxf[2][4];
  #pragma unroll
  for (int nt = 0; nt < 2; nt++){
    #pragma unroll
    for (int c = 0; c < 8; c++)
      whf[nt][c] = *(const u32x4*)(whb + (((size_t)g*HH + k0 + nt*16 + arow)*HH
                                          + qh*256 + c*32 + kq*8));
    #pragma unroll
    for (int c = 0; c < 4; c++)
      wxf[nt][c] = *(const u32x4*)(wxb + (((size_t)g*HH + k0 + nt*16 + arow)*DD
                                          + qh*128 + c*32 + kq*8));
  }
  __syncthreads();

  float creg[8];
  #pragma unroll
  for (int j = 0; j < 8; j++) creg[j] = 0.f;

  for (int t = 0; t < TT; t++){
    // issue xa loads early (latency hides under poll / producer epilogue)
    u32x4 xa[4];
    #pragma unroll
    for (int c = 0; c < 4; c++)
      xa[c] = *(const u32x4*)(xim + ((((size_t)t*4 + g)*BB + b0 + arow)*DD
                                     + qh*128 + c*32 + kq*8));

    f32x4 acc0 = {0.f,0.f,0.f,0.f}, acc1 = {0.f,0.f,0.f,0.f};

    if (t > 0){
      if (wid == 7){   // dedicated poll wave: one coalesced 64B flag load
        const u32* fp = flags + ((size_t)(t-1)*NBG + bg)*16 + (lane & 15);
        while (1){
          u32 v = ld4_sys(fp);
          asm volatile("s_waitcnt vmcnt(0)" ::: "memory");
          __builtin_amdgcn_sched_barrier(0);
          if (__all(v != 0)) break;
          __builtin_amdgcn_s_sleep(1);
        }
      }
      __syncthreads();   // [A] release: hm(t-1) is at MALL

      const u16* hb = hmg + ((size_t)((t-1)&1)*NBG + bg)*(4*16*HH);
      u32x4 ha[8];
      #pragma unroll
      for (int c = 0; c < 8; c++)
        ha[c] = ld16_sys(hb + ((g*16 + arow)*HH + qh*256 + c*32 + kq*8));
      asm volatile("s_waitcnt vmcnt(0)" ::: "memory");
      __builtin_amdgcn_sched_barrier(0);
      #pragma unroll
      for (int c = 0; c < 4; c++){
        acc0 = __builtin_amdgcn_mfma_f32_16x16x32_bf16(as_b8(xa[c]), as_b8(wxf[0][c]), acc0, 0,0,0);
        acc1 = __builtin_amdgcn_mfma_f32_16x16x32_bf16(as_b8(xa[c]), as_b8(wxf[1][c]), acc1, 0,0,0);
      }
      #pragma unroll
      for (int c = 0; c < 8; c++){
        acc0 = __builtin_amdgcn_mfma_f32_16x16x32_bf16(as_b8(ha[c]), as_b8(whf[0][c]), acc0, 0,0,0);
        acc1 = __builtin_amdgcn_mfma_f32_16x16x32_bf16(as_b8(ha[c]), as_b8(whf[1][c]), acc1, 0,0,0);
      }
    } else {
      #pragma unroll
      for (int c = 0; c < 4; c++){
        acc0 = __builtin_amdgcn_mfma_f32_16x16x32_bf16(as_b8(xa[c]), as_b8(wxf[0][c]), acc0, 0,0,0);
        acc1 = __builtin_amdgcn_mfma_f32_16x16x32_bf16(as_b8(xa[c]), as_b8(wxf[1][c]), acc1, 0,0,0);
      }
    }

    // D-layout (m89): b_local = (lane>>4)*4 + reg, k_local = nt*16 + (lane&15)
    #pragma unroll
    for (int r = 0; r < 4; r++){
      pl[wid][kq*4 + r][arow]      = acc0[r];
      pl[wid][kq*4 + r][16 + arow] = acc1[r];
    }
    __syncthreads();   // [B] pl complete

    if (wid == 0){     // full epilogue in one wave: 8 cells per lane
      const int eb = lane >> 2, ek8 = (lane & 3) * 8;
      float hv8[8];
      #pragma unroll
      for (int j = 0; j < 8; j++){
        const int k = ek8 + j;
        float g0 = pl[0][eb][k] + pl[4][eb][k] + bl[0][k];
        float g1 = pl[1][eb][k] + pl[5][eb][k] + bl[1][k];
        float g2 = pl[2][eb][k] + pl[6][eb][k] + bl[2][k];
        float g3 = pl[3][eb][k] + pl[7][eb][k] + bl[3][k];
        float iv = 1.f/(1.f + __expf(-g0));
        float fv = 1.f/(1.f + __expf(-g1));
        float ov = 1.f/(1.f + __expf(-g2));
        float e2g = __expf(2.f*g3);
        float gc = 1.f - 2.f/(e2g + 1.f);          // tanh(g)
        creg[j] = fv*creg[j] + iv*gc;
        float e2c = __expf(2.f*creg[j]);
        float th = 1.f - 2.f/(e2c + 1.f);          // tanh(c)
        hv8[j] = ov*th;
      }
      // hm stores (critical path) -> drain -> flag
      u16* hwb = hmg + ((size_t)(t&1)*NBG + bg)*(4*16*HH);
      #pragma unroll
      for (int gg = 0; gg < 4; gg++){
        union { u16 s[8]; u32x4 v; } o;
        #pragma unroll
        for (int j = 0; j < 8; j++)
          o.s[j] = f2b(hv8[j] * zhl[gg][eb][ek8 + j]);
        st16_sys(hwb + (gg*16 + eb)*HH + k0 + ek8, o.v);
      }
      asm volatile("s_waitcnt vmcnt(0)" ::: "memory");   // hm durable at MALL
      if (lane == 0)
        st4_sys((void*)(flags + ((size_t)t*NBG + bg)*16 + ks), 1u);
      // outputs (off the critical path)
      float* hp = hn + (size_t)t*BB*HH + (size_t)(b0 + eb)*HH + k0 + ek8;
      *(float4*)hp       = make_float4(hv8[0], hv8[1], hv8[2], hv8[3]);
      *(float4*)(hp + 4) = make_float4(hv8[4], hv8[5], hv8[6], hv8[7]);
      if (t == TT-1){
        float* hq = htc + (size_t)(b0 + eb)*HH + k0 + ek8;
        *(float4*)hq       = make_float4(hv8[0], hv8[1], hv8[2], hv8[3]);
        *(float4*)(hq + 4) = make_float4(hv8[4], hv8[5], hv8[6], hv8[7]);
        float* cq = hq + (size_t)BB*HH;
        *(float4*)cq       = make_float4(creg[0], creg[1], creg[2], creg[3]);
        *(float4*)(cq + 4) = make_float4(creg[4], creg[5], creg[6], creg[7]);
      }
    }
    // no barrier here: waves only overwrite pl(t+1) after seeing flags(t),
    // which wave 0 stores only after its pl reads are done.
  }
}

// ---------------------------------------------------------------------------
extern "C" void kernel_launch(void* const* d_in, const int* in_sizes, int n_in,
                              void* d_out, int out_size, void* d_ws, size_t ws_size,
                              hipStream_t stream){
  const float* input   = (const float*)d_in[0];
  const float* ux      = (const float*)d_in[1];
  const float* uh      = (const float*)d_in[2];
  const float* p_logit = (const float*)d_in[3];
  const float* Wx      = (const float*)d_in[4];
  const float* bx      = (const float*)d_in[5];
  const float* Wh      = (const float*)d_in[6];
  const float* bh      = (const float*)d_in[7];

  char* ws = (char*)d_ws;
  const size_t o_zx  = 0;                        // 4*B*D f32      = 524288
  const size_t o_zh  = o_zx  + 524288;           // 4*B*H f32      = 1048576
  const size_t o_b   = o_zh  + 1048576;          // 4*H f32        = 8192
  const size_t o_wxb = o_b   + 8192;             // 4*H*D bf16     = 1048576
  const size_t o_whb = o_wxb + 1048576;          // 4*H*H bf16     = 2097152
  const size_t o_xim = o_whb + 2097152;          // T*4*B*D bf16   = 134217728
  const size_t o_hmg = o_xim + 134217728;        // 2*8*4*16*H bf16= 1048576
  const size_t o_flg = o_hmg + 1048576;          // T*8*16 u32     = 262144
  const size_t need  = o_flg + 262144;
  if (ws_size < need) return;

  float* zx   = (float*)(ws + o_zx);
  float* zh   = (float*)(ws + o_zh);
  float* bias = (float*)(ws + o_b);
  u16*   wxb  = (u16*)(ws + o_wxb);
  u16*   whb  = (u16*)(ws + o_whb);
  u16*   xim  = (u16*)(ws + o_xim);
  u16*   hmg  = (u16*)(ws + o_hmg);
  u32*   flg  = (u32*)(ws + o_flg);

  float* out_hn = (float*)d_out;
  float* out_ht = out_hn + (size_t)TT*BB*HH;

  setup_kernel<<<7944, 256, 0, stream>>>(ux, uh, p_logit, bx, bh, Wx, Wh,
                                         zx, zh, bias, wxb, whb, flg);
  xim_kernel<<<8192, 256, 0, stream>>>(input, zx, xim);
  lstm_persist<<<NBG*NKS, 512, 0, stream>>>(xim, whb, wxb, zh, bias,
                                            hmg, flg, out_hn, out_ht);
}

// Round 5
// 2283.370 us; speedup vs baseline: 1.1985x; 1.1985x over previous
//
#include <hip/hip_runtime.h>
#include <hip/hip_bf16.h>
#include <math.h>

#define TT 512
#define BB 128
#define DD 256
#define HH 512
#define EPSF 1e-7f
#define NBG 8     // b-groups of 16 rows (independent LSTM chains)
#define NKS 16    // k-slices of 32 cols per b-group

typedef unsigned int u32;
typedef unsigned short u16;
typedef __attribute__((ext_vector_type(8))) short bf16x8;
typedef __attribute__((ext_vector_type(4))) float f32x4;
typedef __attribute__((ext_vector_type(4))) u32 u32x4;

__device__ __forceinline__ u16 f2b(float x){
  __hip_bfloat16 b = __float2bfloat16(x);
  union { __hip_bfloat16 h; u16 u; } c; c.h = b; return c.u;
}
__device__ __forceinline__ bf16x8 as_b8(u32x4 u){
  union { u32x4 a; bf16x8 b; } c; c.a = u; return c.b;
}
// system-scope (MALL-coherent) ops: bypass L1+L2, no wbl2/inv needed anywhere
__device__ __forceinline__ void st16_sys(void* p, u32x4 v){
  asm volatile("global_store_dwordx4 %0, %1, off sc0 sc1" :: "v"(p), "v"(v) : "memory");
}
__device__ __forceinline__ u32x4 ld16_sys(const void* p){
  u32x4 r;
  asm volatile("global_load_dwordx4 %0, %1, off sc0 sc1" : "=v"(r) : "v"(p) : "memory");
  return r;
}
__device__ __forceinline__ void st4_sys(void* p, u32 v){
  asm volatile("global_store_dword %0, %1, off sc0 sc1" :: "v"(p), "v"(v) : "memory");
}
__device__ __forceinline__ u32 ld4_sys(const void* p){
  u32 r;
  asm volatile("global_load_dword %0, %1, off sc0 sc1" : "=v"(r) : "v"(p) : "memory");
  return r;
}

// ---------------------------------------------------------------------------
// Setup: masks zx/zh, combined bias, bf16 Wx/Wh, zeroed per-block flags.
// ---------------------------------------------------------------------------
__global__ void setup_kernel(const float* __restrict__ ux, const float* __restrict__ uh,
                             const float* __restrict__ p_logit,
                             const float* __restrict__ bx, const float* __restrict__ bh,
                             const float* __restrict__ Wx, const float* __restrict__ Wh,
                             float* __restrict__ zx, float* __restrict__ zh,
                             float* __restrict__ bias,
                             u16* __restrict__ wxb, u16* __restrict__ whb,
                             u32* __restrict__ flags){
  const int i = blockIdx.x*256 + threadIdx.x;
  const float p = 1.0f/(1.0f+expf(-p_logit[0]));
  const float lp = logf(p+EPSF) - logf(1.0f-p+EPSF);
  const float inv1mp = 1.0f/(1.0f-p);
  const int S1 = 4*BB*DD;             // zx end      131072
  const int S2 = S1 + 4*BB*HH;        // zh end      393216
  const int S3 = S2 + 4*HH;           // bias end    395264
  const int S4 = S3 + 4*HH*DD;        // wxb end     919552
  const int S5 = S4 + 4*HH*HH;        // whb end     1968128
  const int S6 = S5 + TT*NBG*16;      // flags end   2033664
  if (i < S1){
    float u = ux[i];
    float l = (lp + logf(u+EPSF) - logf(1.0f-u+EPSF)) * 10.0f;  // /TEMP
    zx[i] = (1.0f - 1.0f/(1.0f+expf(-l))) * inv1mp;
  } else if (i < S2){
    int j = i - S1;
    float u = uh[j];
    float l = (lp + logf(u+EPSF) - logf(1.0f-u+EPSF)) * 10.0f;
    zh[j] = (1.0f - 1.0f/(1.0f+expf(-l))) * inv1mp;
  } else if (i < S3){
    int j = i - S2;
    bias[j] = bx[j] + bh[j];
  } else if (i < S4){
    int j = i - S3;
    wxb[j] = f2b(Wx[j]);
  } else if (i < S5){
    int j = i - S4;
    whb[j] = f2b(Wh[j]);
  } else if (i < S6){
    flags[i - S5] = 0u;
  }
}

// ---------------------------------------------------------------------------
// xim[t][g][b][d] = bf16(input[t][b][d] * zx[g][b][d]); input read once.
// ---------------------------------------------------------------------------
__global__ void xim_kernel(const float* __restrict__ input, const float* __restrict__ zx,
                           u16* __restrict__ xim){
  const int i = blockIdx.x*256 + threadIdx.x;   // (t,b,d-octet)
  const int d = (i & 31) * 8;
  const int rest = i >> 5;             // t*BB + b
  const int b = rest & (BB-1);
  const int t = rest >> 7;
  const float* ip = input + ((size_t)t*BB + b)*DD + d;
  const float4 x0 = *(const float4*)ip;
  const float4 x1 = *(const float4*)(ip+4);
  #pragma unroll
  for (int g = 0; g < 4; g++){
    const float* zp = zx + ((size_t)g*BB + b)*DD + d;
    const float4 z0 = *(const float4*)zp;
    const float4 z1 = *(const float4*)(zp+4);
    union { u16 s[8]; uint4 v; } o;
    o.s[0]=f2b(x0.x*z0.x); o.s[1]=f2b(x0.y*z0.y); o.s[2]=f2b(x0.z*z0.z); o.s[3]=f2b(x0.w*z0.w);
    o.s[4]=f2b(x1.x*z1.x); o.s[5]=f2b(x1.y*z1.y); o.s[6]=f2b(x1.z*z1.z); o.s[7]=f2b(x1.w*z1.w);
    *(uint4*)(xim + (((size_t)t*4 + g)*BB + b)*DD + d) = o.v;
  }
}

// ---------------------------------------------------------------------------
// Persistent LSTM: 128 blocks = 8 b-groups(16 b) x 16 k-slices(32 k).
// 512 threads = 8 waves = (gate g) x (K-half qh). Weights register-resident.
// Per step: x-MFMAs issue before the sync point; wave 7 polls 16 flags with
// one 64B load; all 512 threads run the epilogue (1 cell each); role-split
// tail: wave0 stores hm + drains + stores flag, waves 1-2 store hn from LDS.
// ---------------------------------------------------------------------------
__global__ __launch_bounds__(512, 2)
void lstm_persist(const u16* __restrict__ xim,   // [T][4][B][D]
                  const u16* __restrict__ whb,   // [4][H][H]
                  const u16* __restrict__ wxb,   // [4][H][D]
                  const float* __restrict__ zh,  // [4][B][H]
                  const float* __restrict__ bias,// [4][H]
                  u16* __restrict__ hmg,         // [2][NBG][4][16][H]
                  u32* __restrict__ flags,       // [T][NBG][16]
                  float* __restrict__ hn,        // [T][B][H]
                  float* __restrict__ htc)       // [2][B][H]
{
  __shared__ float pl[8][16][36];   // partial gates [wid][b_local][k_local], padded
  __shared__ u16 hml[4][16][32];    // staged masked-h (bf16) for wave0 writeout
  __shared__ float hnl[16][32];     // staged h (f32) for waves1-2 writeout

  const int bid = blockIdx.x;
  const int bg = bid & 7, ks = bid >> 3;
  const int b0 = bg*16, k0 = ks*32;
  const int tid = threadIdx.x;
  const int wid = tid >> 6, lane = tid & 63;
  const int g = wid & 3, qh = wid >> 2;
  const int arow = lane & 15, kq = lane >> 4;

  // ---- weights into registers ----
  u32x4 whf[2][8], wxf[2][4];
  #pragma unroll
  for (int nt = 0; nt < 2; nt++){
    #pragma unroll
    for (int c = 0; c < 8; c++)
      whf[nt][c] = *(const u32x4*)(whb + (((size_t)g*HH + k0 + nt*16 + arow)*HH
                                          + qh*256 + c*32 + kq*8));
    #pragma unroll
    for (int c = 0; c < 4; c++)
      wxf[nt][c] = *(const u32x4*)(wxb + (((size_t)g*HH + k0 + nt*16 + arow)*DD
                                          + qh*128 + c*32 + kq*8));
  }

  // per-thread epilogue constants (1 cell per thread)
  const int ebl = tid >> 5, ekl = tid & 31;
  float bias4[4], zhe[4];
  #pragma unroll
  for (int gg = 0; gg < 4; gg++){
    bias4[gg] = bias[gg*HH + k0 + ekl];
    zhe[gg]   = zh[((size_t)gg*BB + b0 + ebl)*HH + k0 + ekl];
  }
  float creg = 0.f;

  for (int t = 0; t < TT; t++){
    // xa loads + x-MFMAs: independent of the exchange, overlap the wait
    u32x4 xa[4];
    #pragma unroll
    for (int c = 0; c < 4; c++)
      xa[c] = *(const u32x4*)(xim + ((((size_t)t*4 + g)*BB + b0 + arow)*DD
                                     + qh*128 + c*32 + kq*8));
    f32x4 acc0 = {0.f,0.f,0.f,0.f}, acc1 = {0.f,0.f,0.f,0.f};
    #pragma unroll
    for (int c = 0; c < 4; c++){
      acc0 = __builtin_amdgcn_mfma_f32_16x16x32_bf16(as_b8(xa[c]), as_b8(wxf[0][c]), acc0, 0,0,0);
      acc1 = __builtin_amdgcn_mfma_f32_16x16x32_bf16(as_b8(xa[c]), as_b8(wxf[1][c]), acc1, 0,0,0);
    }

    if (t > 0){
      if (wid == 7){   // poll all 16 producer flags in one coalesced 64B load
        const u32* fp = flags + ((size_t)(t-1)*NBG + bg)*16 + (lane & 15);
        while (1){
          u32 v = ld4_sys(fp);
          asm volatile("s_waitcnt vmcnt(0)" ::: "memory");
          __builtin_amdgcn_sched_barrier(0);
          if (__all(v != 0)) break;
          __builtin_amdgcn_s_sleep(1);
        }
      }
      __syncthreads();   // [A] hm(t-1) is durable at MALL

      const u16* hb = hmg + ((size_t)((t-1)&1)*NBG + bg)*(4*16*HH);
      u32x4 ha[8];
      #pragma unroll
      for (int c = 0; c < 8; c++)
        ha[c] = ld16_sys(hb + ((g*16 + arow)*HH + qh*256 + c*32 + kq*8));
      asm volatile("s_waitcnt vmcnt(0)" ::: "memory");
      __builtin_amdgcn_sched_barrier(0);
      #pragma unroll
      for (int c = 0; c < 8; c++){
        acc0 = __builtin_amdgcn_mfma_f32_16x16x32_bf16(as_b8(ha[c]), as_b8(whf[0][c]), acc0, 0,0,0);
        acc1 = __builtin_amdgcn_mfma_f32_16x16x32_bf16(as_b8(ha[c]), as_b8(whf[1][c]), acc1, 0,0,0);
      }
    }

    // D-frag: b_local = kq*4+r, k_local = nt*16 + arow
    #pragma unroll
    for (int r = 0; r < 4; r++){
      pl[wid][kq*4 + r][arow]      = acc0[r];
      pl[wid][kq*4 + r][16 + arow] = acc1[r];
    }
    __syncthreads();   // [B] pl complete

    { // epilogue: all 512 threads, one (b,k) cell each
      float g0 = pl[g? 0:0][0][0]; // (placeholder no-op to keep indices clear)
      float gv[4];
      #pragma unroll
      for (int gg = 0; gg < 4; gg++)
        gv[gg] = pl[gg][ebl][ekl] + pl[4+gg][ebl][ekl] + bias4[gg];
      (void)g0;
      float iv = 1.f/(1.f + __expf(-gv[0]));
      float fv = 1.f/(1.f + __expf(-gv[1]));
      float ov = 1.f/(1.f + __expf(-gv[2]));
      float e2g = __expf(2.f*gv[3]);
      float gc = 1.f - 2.f/(e2g + 1.f);          // tanh(g)
      creg = fv*creg + iv*gc;
      float e2c = __expf(2.f*creg);
      float th = 1.f - 2.f/(e2c + 1.f);          // tanh(c)
      float hv = ov*th;
      #pragma unroll
      for (int gg = 0; gg < 4; gg++)
        hml[gg][ebl][ekl] = f2b(hv * zhe[gg]);
      hnl[ebl][ekl] = hv;
      if (t == TT-1){
        const size_t ci = (size_t)(b0 + ebl)*HH + k0 + ekl;
        htc[ci] = hv;
        htc[(size_t)BB*HH + ci] = creg;
      }
    }
    __syncthreads();   // [C] hml/hnl staged

    if (wid == 0){
      // hm: 4x 16B per lane -> drain -> flag (the inter-block critical path)
      u16* hwb = hmg + ((size_t)(t&1)*NBG + bg)*(4*16*HH);
      const int ob = lane >> 2, oq = lane & 3;
      #pragma unroll
      for (int c = 0; c < 4; c++){
        u32x4 v = *(const u32x4*)&hml[c][ob][oq*8];
        st16_sys(hwb + (c*16 + ob)*HH + k0 + oq*8, v);
      }
      asm volatile("s_waitcnt vmcnt(0)" ::: "memory");
      if (lane == 0)
        st4_sys((void*)(flags + ((size_t)t*NBG + bg)*16 + ks), 1u);
    } else if (wid == 1 || wid == 2){
      // hn outputs: off the critical path
      const int idx = (wid-1)*64 + lane;          // 0..127
      const int ob = idx >> 3, oq = (idx & 7)*4;
      float4 v = *(const float4*)&hnl[ob][oq];
      *(float4*)(hn + (size_t)t*BB*HH + (size_t)(b0 + ob)*HH + k0 + oq) = v;
    }
    // no tail barrier: [A] of t+1 orders everything (waves can't write
    // pl(t+1) until wave0/1/2 finish duties and arrive there).
  }
}

// ---------------------------------------------------------------------------
extern "C" void kernel_launch(void* const* d_in, const int* in_sizes, int n_in,
                              void* d_out, int out_size, void* d_ws, size_t ws_size,
                              hipStream_t stream){
  const float* input   = (const float*)d_in[0];
  const float* ux      = (const float*)d_in[1];
  const float* uh      = (const float*)d_in[2];
  const float* p_logit = (const float*)d_in[3];
  const float* Wx      = (const float*)d_in[4];
  const float* bx      = (const float*)d_in[5];
  const float* Wh      = (const float*)d_in[6];
  const float* bh      = (const float*)d_in[7];

  char* ws = (char*)d_ws;
  const size_t o_zx  = 0;                        // 4*B*D f32      = 524288
  const size_t o_zh  = o_zx  + 524288;           // 4*B*H f32      = 1048576
  const size_t o_b   = o_zh  + 1048576;          // 4*H f32        = 8192
  const size_t o_wxb = o_b   + 8192;             // 4*H*D bf16     = 1048576
  const size_t o_whb = o_wxb + 1048576;          // 4*H*H bf16     = 2097152
  const size_t o_xim = o_whb + 2097152;          // T*4*B*D bf16   = 134217728
  const size_t o_hmg = o_xim + 134217728;        // 2*8*4*16*H bf16= 1048576
  const size_t o_flg = o_hmg + 1048576;          // T*8*16 u32     = 262144
  const size_t need  = o_flg + 262144;
  if (ws_size < need) return;

  float* zx   = (float*)(ws + o_zx);
  float* zh   = (float*)(ws + o_zh);
  float* bias = (float*)(ws + o_b);
  u16*   wxb  = (u16*)(ws + o_wxb);
  u16*   whb  = (u16*)(ws + o_whb);
  u16*   xim  = (u16*)(ws + o_xim);
  u16*   hmg  = (u16*)(ws + o_hmg);
  u32*   flg  = (u32*)(ws + o_flg);

  float* out_hn = (float*)d_out;
  float* out_ht = out_hn + (size_t)TT*BB*HH;

  setup_kernel<<<7944, 256, 0, stream>>>(ux, uh, p_logit, bx, bh, Wx, Wh,
                                         zx, zh, bias, wxb, whb, flg);
  xim_kernel<<<8192, 256, 0, stream>>>(input, zx, xim);
  lstm_persist<<<NBG*NKS, 512, 0, stream>>>(xim, whb, wxb, zh, bias,
                                            hmg, flg, out_hn, out_ht);
}